// Round 22
// baseline (128.820 us; speedup 1.0000x reference)
//
#include <hip/hip_runtime.h>
#include <hip/hip_bf16.h>
#include <cstdint>
#include <cstddef>

// ---------------------------------------------------------------------------
// YiJingAttention: x[B,T,C] -> qkv -> causal attn (+rank-1 trigram bias) -> out
// B=2 T=2048 C=1024 H=8 hd=128. All internal matmuls in bf16 MFMA, f32 accum.
// FINAL configuration = measured best, reproduced 4x (128.7-129.2 us):
//   k_prep (cast+transpose fused) -> k_gemm 128^2 (GEMM1) -> k_attn
//   (split-kv flash, nc<=3 LPT schedule, 4 waves x 32 q-rows) -> k_fin
//   (combine+transpose fused) -> k_gemm (GEMM2, f32 out).
// Probed-and-rejected (all measured): 256^2 GEMM tiles (r12/13/15), XCD
// block swizzle (r16), 3-block attn occupancy (r8 spill / r11 null), finer
// nc<=4 splits (r18), 8-wave x 16-row attn (r20). The attn kernel sits at
// the measured optimum of the work-per-wave vs TLP tradeoff.
// ---------------------------------------------------------------------------

namespace {
constexpr int kB = 2, kT = 2048, kC = 1024, kHD = 128;
constexpr int kM = kB * kT;   // 4096 rows
constexpr int kN3 = 3 * kC;   // 3072
constexpr float kScale = 0.08838834764831845f;   // 1/sqrt(128)
constexpr float kInvS3 = 0.57735026918962576f;   // 1/sqrt(3)
constexpr float kL2E  = 1.4426950408889634f;     // log2(e)
}

typedef __bf16 bf16x8 __attribute__((ext_vector_type(8)));
typedef float f32x4 __attribute__((ext_vector_type(4)));
typedef unsigned short u16x8 __attribute__((ext_vector_type(8)));
typedef unsigned short u16x4 __attribute__((ext_vector_type(4)));
typedef unsigned int u32x4 __attribute__((ext_vector_type(4)));

__device__ __forceinline__ unsigned short f2b(float f) {
  return __builtin_bit_cast(unsigned short, (__bf16)f);
}
__device__ __forceinline__ float b2f(unsigned short u) {
  return (float)__builtin_bit_cast(__bf16, u);
}
// async global->LDS, 16B per lane. lds must be wave-uniform base (HW adds lane*16).
__device__ __forceinline__ void gll16(const void* g, void* lds) {
  __builtin_amdgcn_global_load_lds(
      (const __attribute__((address_space(1))) unsigned int*)g,
      (__attribute__((address_space(3))) unsigned int*)lds, 16, 0, 0);
}
__device__ __forceinline__ bf16x8 ldsv(const unsigned short* p) {
  return __builtin_bit_cast(bf16x8, *(const u16x8*)p);
}
// hardware transpose read (m156/m162): 16-lane group collectively reads its
// 4x16 bf16 row-major subtile; lane receives column (lane&15) as 4 bf16.
__device__ __forceinline__ uint2 tr16(const unsigned short* p) {
  uint2 r;
  unsigned off = (unsigned)(uintptr_t)(const __attribute__((address_space(3))) unsigned short*)p;
  asm volatile("ds_read_b64_tr_b16 %0, %1" : "=v"(r) : "v"(off));
  return r;
}

// ---------------- transpose+cast device body (in[R][Cin]f32 -> out[Cin][R]) --
__device__ __forceinline__ void tc_body(const float* __restrict__ in,
                                        unsigned short* __restrict__ out,
                                        int R, int Cin, int bx, int by, int t) {
  __shared__ float tile[64][65];
  const int r0 = by * 64, c0 = bx * 64;
  const int tr = t >> 4, tc4 = (t & 15) * 4;
#pragma unroll
  for (int rr = 0; rr < 4; ++rr) {
    int r = tr + rr * 16;
    float4 v = *(const float4*)&in[(size_t)(r0 + r) * Cin + c0 + tc4];
    tile[r][tc4 + 0] = v.x; tile[r][tc4 + 1] = v.y;
    tile[r][tc4 + 2] = v.z; tile[r][tc4 + 3] = v.w;
  }
  __syncthreads();
#pragma unroll
  for (int rr = 0; rr < 4; ++rr) {
    int c = tr + rr * 16;
    u16x4 o = { f2b(tile[tc4 + 0][c]), f2b(tile[tc4 + 1][c]),
                f2b(tile[tc4 + 2][c]), f2b(tile[tc4 + 3][c]) };
    *(u16x4*)&out[(size_t)(c0 + c) * R + r0 + tc4] = o;
  }
}

// ------ k_prep: blocks [0,4096) cast x->bf16; [4096,4864) transpose wqkv ----
__global__ void k_prep(const float* __restrict__ x, unsigned short* __restrict__ xb,
                       const float* __restrict__ wqkv, unsigned short* __restrict__ wqkvT) {
  const int bid = (int)blockIdx.x;
  const int t = threadIdx.x;
  if (bid < 4096) {
    int i = bid * 256 + t;                      // n4 = 4096*256 exactly
    float4 v = ((const float4*)x)[i];
    u16x4 o = { f2b(v.x), f2b(v.y), f2b(v.z), f2b(v.w) };
    ((u16x4*)xb)[i] = o;
  } else {
    int r = bid - 4096;                         // 768 blocks: 48 x 16
    tc_body(wqkv, wqkvT, kC, kN3, r % 48, r / 48, t);
  }
}

// ----------------- 128x128 bf16 MFMA GEMM, Bt is [N][K] --------------------
// Natural (bx,by) mapping, NO block swizzle (XCD remap measured -1.7us, r16).
__global__ __launch_bounds__(256, 2) void k_gemm(
    const unsigned short* __restrict__ A,
    const unsigned short* __restrict__ Bt,
    unsigned short* __restrict__ Cb,
    float* __restrict__ Cf,
    int M, int N, int K, int ldc) {
  __shared__ unsigned short sA[2][4096];
  __shared__ unsigned short sB[2][4096];
  const int t = threadIdx.x;
  const int lane = t & 63, wave = t >> 6;
  const int g = lane >> 4, c16 = lane & 15;
  const int wr = wave >> 1, wc = wave & 1;
  const int brow = blockIdx.x * 128, bcol = blockIdx.y * 128;
  const int NT = K >> 5;

  f32x4 acc[4][4];
#pragma unroll
  for (int m = 0; m < 4; ++m)
#pragma unroll
    for (int n = 0; n < 4; ++n) acc[m][n] = 0.f;

  auto stage = [&](int buf, int kt) {
    const int k0 = kt * 32;
#pragma unroll
    for (int is = 0; is < 2; ++is) {
      int row = is * 64 + (t >> 2);
      int gs = (t & 3) ^ (row & 3);
      gll16(&A[(size_t)(brow + row) * K + k0 + gs * 8], &sA[buf][is * 2048 + wave * 512]);
      gll16(&Bt[(size_t)(bcol + row) * K + k0 + gs * 8], &sB[buf][is * 2048 + wave * 512]);
    }
  };

  stage(0, 0);
  __syncthreads();
  for (int kt = 0; kt < NT; ++kt) {
    if (kt + 1 < NT) stage((kt + 1) & 1, kt + 1);
    const int buf = kt & 1;
    bf16x8 av[4], bv[4];
#pragma unroll
    for (int m = 0; m < 4; ++m) {
      int row = wr * 64 + m * 16 + c16;
      av[m] = ldsv(&sA[buf][row * 32 + (g ^ (row & 3)) * 8]);
    }
#pragma unroll
    for (int n = 0; n < 4; ++n) {
      int row = wc * 64 + n * 16 + c16;
      bv[n] = ldsv(&sB[buf][row * 32 + (g ^ (row & 3)) * 8]);
    }
    __builtin_amdgcn_s_setprio(1);
#pragma unroll
    for (int m = 0; m < 4; ++m)
#pragma unroll
      for (int n = 0; n < 4; ++n)
        acc[m][n] = __builtin_amdgcn_mfma_f32_16x16x32_bf16(av[m], bv[n], acc[m][n], 0, 0, 0);
    __builtin_amdgcn_s_setprio(0);
    __syncthreads();
  }

  const int orow = brow + wr * 64, ocol = bcol + wc * 64;
  if (Cb != nullptr) {
#pragma unroll
    for (int m = 0; m < 4; ++m)
#pragma unroll
      for (int n = 0; n < 4; ++n)
#pragma unroll
        for (int jj = 0; jj < 4; ++jj)
          Cb[(size_t)(orow + m * 16 + g * 4 + jj) * ldc + ocol + n * 16 + c16] =
              f2b(acc[m][n][jj]);
  } else {
#pragma unroll
    for (int m = 0; m < 4; ++m)
#pragma unroll
      for (int n = 0; n < 4; ++n)
#pragma unroll
        for (int jj = 0; jj < 4; ++jj)
          Cf[(size_t)(orow + m * 16 + g * 4 + jj) * ldc + ocol + n * 16 + c16] =
              acc[m][n][jj];
  }
}

// ---------------- flash attention (split-kv, 128-row q-tiles) --------------
// 256 threads = 4 waves x 32 q-rows. Single-buffered sK, dbuf subtiled sV +
// tr16 HW-transpose reads, LPT split schedule (44 items, nc<=3, sizes 2..11
// size-descending), defer-max (T13), in-register P s-frag->A-frag
// redistribution. Blocks write UNNORMALIZED partial O (bf16) + per-row
// (m,l); k_fin merges <=3 chunks.
__constant__ unsigned char kItem[44] = {
  60, 61,                       // 11 tiles
  62, 56, 57, 58, 52,           // 10
  53, 54, 48, 49,               // 9
  50, 44, 45, 46, 40,           // 8
  41, 42, 36, 37,               // 7
  38, 32, 33, 34, 28,           // 6
  29, 30, 24, 25,               // 5
  26, 20, 21, 22, 16,           // 4
  17, 18, 12, 13, 8, 9,         // 3
  14, 4, 5, 0 };                // 2

__global__ __launch_bounds__(256, 2) void k_attn(
    const unsigned short* __restrict__ qkv,
    const float* __restrict__ head_scales,
    unsigned short* __restrict__ pO0,    // chunk0 partial, final layout [4096][1024]
    unsigned short* __restrict__ pO1,    // chunk1 partial
    unsigned short* __restrict__ pO2,    // chunk2 partial
    float2* __restrict__ pml) {          // [3][16][16][128] (m,l)
  __shared__ unsigned short sK[8192];     // 64 rows x 128 k, XOR-swizzled (single)
  __shared__ unsigned short sV[2][8192];  // [dn 8][kv4 16][4][16] subtiled (dbuf)
  __shared__ float sKp[2][64];

  const int t = threadIdx.x;
  const int lane = t & 63, wave = t >> 6;
  const int g = lane >> 4, c16 = lane & 15;
  const int bh = blockIdx.x;                  // same-bh blocks share an XCD L2
  const int it = kItem[blockIdx.y];
  const int qt = it >> 2, c = it & 3;
  const int n = 2 * qt + 2;
  const int nc = (qt == 0) ? 1 : (qt <= 2) ? 2 : 3;
  const int cbase = n / nc, crem = n % nc;
  const int t0 = c * cbase + (c < crem ? c : crem);
  const int t1 = t0 + cbase + (c < crem ? 1 : 0);

  const int b = bh >> 3, h = bh & 7;
  const float hs = head_scales[h];
  const float sx = (h & 4) ? 1.f : -1.f;
  const float sy = (h & 2) ? 1.f : -1.f;
  const float sz = (h & 1) ? 1.f : -1.f;

  const int q0w = qt * 128 + wave * 32;       // this wave's 32 q-rows
  const size_t rowbase = (size_t)b * kT;

  // Q fragments (B-operand) + per-row bias projection, both 16-row halves
  bf16x8 aq[2][4];
  float qp[2];
#pragma unroll
  for (int m = 0; m < 2; ++m) {
    const unsigned short* qrow = &qkv[(rowbase + q0w + m * 16 + c16) * kN3 + h * kHD];
#pragma unroll
    for (int ks = 0; ks < 4; ++ks) aq[m][ks] = ldsv(qrow + ks * 32 + g * 8);
    qp[m] = hs * kInvS3 * (sx * b2f(qrow[0]) + sy * b2f(qrow[1]) + sz * b2f(qrow[2]));
  }

  float mrow[2] = { -__builtin_inff(), -__builtin_inff() };
  float lrow[2] = { 0.f, 0.f };
  f32x4 oacc[2][8];
#pragma unroll
  for (int m = 0; m < 2; ++m)
#pragma unroll
    for (int dn = 0; dn < 8; ++dn) oacc[m][dn] = 0.f;

  uint2 kpr;       // kp prefetch (wave 0)

  auto stageK = [&](int jt) {
    const int j0 = jt * 64;
#pragma unroll
    for (int is = 0; is < 4; ++is) {
      int row = is * 16 + (t >> 4);
      int gp = t & 15;
      int gs = (gp & 8) | ((gp ^ (row & 7)) & 7);
      gll16(&qkv[(rowbase + j0 + row) * kN3 + kC + h * kHD + gs * 8],
            &sK[is * 2048 + wave * 512]);
    }
  };
  auto stageV = [&](int jt, int buf) {
    const int j0 = jt * 64;
    const int vrow = ((lane >> 3) << 2) + ((lane >> 1) & 3);
    const int vcol = (lane & 1) * 8;
#pragma unroll
    for (int d = 0; d < 2; ++d) {
      const int dn = wave * 2 + d;
#pragma unroll
      for (int hf2 = 0; hf2 < 2; ++hf2) {
        gll16(&qkv[(rowbase + j0 + hf2 * 32 + vrow) * kN3 + 2 * kC + h * kHD
                   + dn * 16 + vcol],
              &sV[buf][dn * 1024 + hf2 * 512]);
      }
    }
  };
  auto loadKp = [&](int jt) {
    if (wave == 0)
      kpr = *(const uint2*)&qkv[(rowbase + jt * 64 + lane) * kN3 + kC + h * kHD];
  };
  auto writeKp = [&](int buf) {
    if (wave == 0) {
      float e0 = b2f((unsigned short)(kpr.x & 0xffffu));
      float e1 = b2f((unsigned short)(kpr.x >> 16));
      float e2 = b2f((unsigned short)(kpr.y & 0xffffu));
      sKp[buf][lane] = kInvS3 * (sx * e0 + sy * e1 + sz * e2);
    }
  };

  // prologue: first tile of this chunk
  stageK(t0); stageV(t0, 0); loadKp(t0);
  writeKp(0);
  __syncthreads();

  for (int jt = t0; jt < t1; ++jt) {
    const int vbuf = (jt - t0) & 1;
    const bool more = (jt + 1 < t1);
    const int j0 = jt * 64;

    // ---- S^T = K Q^T for both 16-row halves (reads sK, single buffer) ----
    f32x4 s[2][4];
#pragma unroll
    for (int m = 0; m < 2; ++m)
#pragma unroll
      for (int nn = 0; nn < 4; ++nn) s[m][nn] = 0.f;
#pragma unroll
    for (int ks = 0; ks < 4; ++ks) {
      bf16x8 kb[4];
#pragma unroll
      for (int nn = 0; nn < 4; ++nn) {
        int gp = ks * 4 + g;
        int gp2 = (gp & 8) | ((gp ^ (c16 & 7)) & 7);
        kb[nn] = ldsv(&sK[(nn * 16 + c16) * 128 + gp2 * 8]);
      }
      __builtin_amdgcn_s_setprio(1);
#pragma unroll
      for (int m = 0; m < 2; ++m)
#pragma unroll
        for (int nn = 0; nn < 4; ++nn)
          s[m][nn] = __builtin_amdgcn_mfma_f32_16x16x32_bf16(kb[nn], aq[m][ks], s[m][nn], 0, 0, 0);
      __builtin_amdgcn_s_setprio(0);
    }

    __syncthreads();   // B1: all waves done reading sK; safe to restage
    if (more) { stageK(jt + 1); stageV(jt + 1, vbuf ^ 1); loadKp(jt + 1); }

    // ---- bias + causal mask + in-lane online softmax, per half ----
    float kpv[4][4];
#pragma unroll
    for (int nn = 0; nn < 4; ++nn)
#pragma unroll
      for (int jj = 0; jj < 4; ++jj) kpv[nn][jj] = sKp[vbuf][nn * 16 + g * 4 + jj];

    const bool edge = (jt >= 2 * qt);         // two diagonal tiles mask
    unsigned int paf[2][2][4];                // [m][ks2][w] A-frag words
#pragma unroll
    for (int m = 0; m < 2; ++m) {
      const int qg = q0w + m * 16 + c16;
      float vmax = -__builtin_inff();
#pragma unroll
      for (int nn = 0; nn < 4; ++nn)
#pragma unroll
        for (int jj = 0; jj < 4; ++jj) {
          float xv = s[m][nn][jj] * kScale + qp[m] * kpv[nn][jj];
          if (edge) {
            int kvg = j0 + nn * 16 + g * 4 + jj;
            xv = (kvg <= qg) ? xv : -__builtin_inff();
          }
          s[m][nn][jj] = xv;
          vmax = fmaxf(vmax, xv);
        }
      vmax = fmaxf(vmax, __shfl_xor(vmax, 16, 64));
      vmax = fmaxf(vmax, __shfl_xor(vmax, 32, 64));

      // defer-max (T13): rescale only when max grows by more than 8
      if (__any(vmax > mrow[m] + 8.f)) {
        float mnew = fmaxf(mrow[m], vmax);
        float mc0 = fmaxf(mnew, -1e30f);
        float alpha = exp2f((mrow[m] - mc0) * kL2E);   // 0 if mrow=-inf
        mrow[m] = mnew;
        lrow[m] *= alpha;
        float ao[4];
#pragma unroll
        for (int jj = 0; jj < 4; ++jj)
          ao[jj] = __shfl(alpha, (lane & 48) | (g * 4 + jj), 64);
#pragma unroll
        for (int dn = 0; dn < 8; ++dn)
#pragma unroll
          for (int jj = 0; jj < 4; ++jj) oacc[m][dn][jj] *= ao[jj];
      }

      // P = exp(s - m) (bounded by e^8 under defer), packed bf16 pairs
      unsigned int pk[4][2];
      {
        const float mc = fmaxf(mrow[m], -1e30f);
        float ls = 0.f;
#pragma unroll
        for (int nn = 0; nn < 4; ++nn) {
          float p0 = exp2f((s[m][nn][0] - mc) * kL2E);
          float p1 = exp2f((s[m][nn][1] - mc) * kL2E);
          float p2 = exp2f((s[m][nn][2] - mc) * kL2E);
          float p3 = exp2f((s[m][nn][3] - mc) * kL2E);
          ls += (p0 + p1) + (p2 + p3);
          pk[nn][0] = (unsigned)f2b(p0) | ((unsigned)f2b(p1) << 16);
          pk[nn][1] = (unsigned)f2b(p2) | ((unsigned)f2b(p3) << 16);
        }
        lrow[m] += ls;
      }
      // redistribute s-frag -> A-frag in register (verified round 7)
#pragma unroll
      for (int ks2 = 0; ks2 < 2; ++ks2)
#pragma unroll
        for (int w = 0; w < 4; ++w) {
          int src = c16 + (((lane >> 4) & 1) * 2 + (w >> 1)) * 16;
          int va  = __shfl((int)pk[2 * ks2][w & 1], src, 64);
          int vb_ = __shfl((int)pk[2 * ks2 + 1][w & 1], src, 64);
          paf[m][ks2][w] = (unsigned)((lane & 32) ? vb_ : va);
        }
    }

    // ---- O += P V (tr16 B-fragments; V-frag read once, both halves) ----
#pragma unroll
    for (int ks2 = 0; ks2 < 2; ++ks2) {
      bf16x8 pa0 = __builtin_bit_cast(bf16x8,
          (u32x4){paf[0][ks2][0], paf[0][ks2][1], paf[0][ks2][2], paf[0][ks2][3]});
      bf16x8 pa1 = __builtin_bit_cast(bf16x8,
          (u32x4){paf[1][ks2][0], paf[1][ks2][1], paf[1][ks2][2], paf[1][ks2][3]});
      uint2 trv[8][2];
#pragma unroll
      for (int dn = 0; dn < 8; ++dn)
#pragma unroll
        for (int hf = 0; hf < 2; ++hf)
          trv[dn][hf] = tr16(&sV[vbuf][dn * 1024 + (ks2 * 8 + 2 * g + hf) * 64 + c16 * 4]);
      asm volatile("s_waitcnt lgkmcnt(0)" ::: "memory");
      __builtin_amdgcn_sched_barrier(0);
      __builtin_amdgcn_s_setprio(1);
#pragma unroll
      for (int dn = 0; dn < 8; ++dn) {
        bf16x8 vb = __builtin_bit_cast(bf16x8,
            (u32x4){trv[dn][0].x, trv[dn][0].y, trv[dn][1].x, trv[dn][1].y});
        oacc[0][dn] = __builtin_amdgcn_mfma_f32_16x16x32_bf16(pa0, vb, oacc[0][dn], 0, 0, 0);
        oacc[1][dn] = __builtin_amdgcn_mfma_f32_16x16x32_bf16(pa1, vb, oacc[1][dn], 0, 0, 0);
      }
      __builtin_amdgcn_s_setprio(0);
    }

    if (more) {
      writeKp(vbuf ^ 1);
      __syncthreads();   // B2: drains staged sK/sV vmem; next tile ready
    }
  }

  // ---- write partials: (m,l) per row + unnormalized O (bf16) ----
  unsigned short* pout = (c == 0) ? pO0 : (c == 1) ? pO1 : pO2;
#pragma unroll
  for (int m = 0; m < 2; ++m) {
    float lt = lrow[m];
    lt += __shfl_xor(lt, 16, 64);
    lt += __shfl_xor(lt, 32, 64);
    if (g == 0) {
      int rowi = wave * 32 + m * 16 + c16;
      pml[c * 32768 + (bh * 16 + qt) * 128 + rowi] = make_float2(mrow[m], lt);
    }
#pragma unroll
    for (int dn = 0; dn < 8; ++dn)
#pragma unroll
      for (int jj = 0; jj < 4; ++jj) {
        int r = q0w + m * 16 + g * 4 + jj;
        pout[(rowbase + r) * kC + h * kHD + dn * 16 + c16] = f2b(oacc[m][dn][jj]);
      }
  }
}

// ---- k_fin: blocks [0,256) combine partials; [256,512) transpose wout -----
__global__ void k_fin(unsigned short* __restrict__ p0,
                      const unsigned short* __restrict__ p1,
                      const unsigned short* __restrict__ p2,
                      const float2* __restrict__ pml,
                      const float* __restrict__ wout,
                      unsigned short* __restrict__ woutT) {
  const int bid = (int)blockIdx.x;
  const int t = threadIdx.x;
  if (bid >= 256) {
    int r = bid - 256;                          // 256 blocks: 16 x 16
    tc_body(wout, woutT, kC, kC, r & 15, r >> 4, t);
    return;
  }
  const int bh = bid & 15, qt = bid >> 4;
  const int row = t >> 1, half = t & 1;          // 128 rows x 2 half-rows(64)
  const int b = bh >> 3, h = bh & 7;
  const size_t base = ((size_t)b * kT + qt * 128 + row) * kC + h * kHD + half * 64;
  const int nc = (qt == 0) ? 1 : (qt <= 2) ? 2 : 3;
  const int mli = (bh * 16 + qt) * 128 + row;
  float2 ml0 = pml[mli];
  float2 ml1 = make_float2(-1e30f, 0.f), ml2 = make_float2(-1e30f, 0.f);
  float mm = ml0.x;
  if (nc > 1) { ml1 = pml[32768 + mli]; mm = fmaxf(mm, ml1.x); }
  if (nc > 2) { ml2 = pml[65536 + mli]; mm = fmaxf(mm, ml2.x); }
  const float w0 = exp2f((ml0.x - mm) * kL2E);
  const float w1 = (nc > 1) ? exp2f((ml1.x - mm) * kL2E) : 0.f;
  const float w2 = (nc > 2) ? exp2f((ml2.x - mm) * kL2E) : 0.f;
  const float inv = 1.0f / (w0 * ml0.y + w1 * ml1.y + w2 * ml2.y);
#pragma unroll
  for (int i = 0; i < 8; ++i) {
    u16x8 o0 = *(const u16x8*)&p0[base + i * 8];
    u16x8 r;
    if (nc == 1) {
#pragma unroll
      for (int j = 0; j < 8; ++j) r[j] = f2b(b2f(o0[j]) * inv);
    } else if (nc == 2) {
      u16x8 o1 = *(const u16x8*)&p1[base + i * 8];
#pragma unroll
      for (int j = 0; j < 8; ++j)
        r[j] = f2b((w0 * b2f(o0[j]) + w1 * b2f(o1[j])) * inv);
    } else {
      u16x8 o1 = *(const u16x8*)&p1[base + i * 8];
      u16x8 o2 = *(const u16x8*)&p2[base + i * 8];
#pragma unroll
      for (int j = 0; j < 8; ++j)
        r[j] = f2b((w0 * b2f(o0[j]) + w1 * b2f(o1[j]) + w2 * b2f(o2[j])) * inv);
    }
    *(u16x8*)&p0[base + i * 8] = r;
  }
}

// ---------------------------------------------------------------------------
extern "C" void kernel_launch(void* const* d_in, const int* in_sizes, int n_in,
                              void* d_out, int out_size, void* d_ws, size_t ws_size,
                              hipStream_t stream) {
  const float* x    = (const float*)d_in[0];
  const float* wqkv = (const float*)d_in[1];
  const float* wout = (const float*)d_in[2];
  const float* hsc  = (const float*)d_in[3];
  char* ws = (char*)d_ws;
  // workspace (48MB exactly):
  //   [0,8M)     xb (GEMM1 A)         -> attn partial1
  //   [8M,16M)   wqkvT (6.3M of 8M)   -> attn partial2
  //   [16M,40M)  qkvb (24M)           -> woutT (first 2M, after attn)
  //   [40M,48M)  attnb: partial0 -> final attn out (in place)
  // (m,l) table lives in d_out (16.8M f32) -- GEMM2 fully overwrites it after.
  unsigned short* xb    = (unsigned short*)(ws);
  unsigned short* wqkvT = (unsigned short*)(ws + 8388608);
  unsigned short* qkvb  = (unsigned short*)(ws + 16777216);
  unsigned short* attnb = (unsigned short*)(ws + 41943040);
  unsigned short* woutT = (unsigned short*)(ws + 16777216);   // reuses qkvb
  float2* pml = (float2*)d_out;
  float* out = (float*)d_out;

  k_prep<<<dim3(4864), dim3(256), 0, stream>>>(x, xb, wqkv, wqkvT);
  k_gemm<<<dim3(32, 24), dim3(256), 0, stream>>>(xb, wqkvT, qkvb, nullptr, kM, kN3, kC, kN3);
  k_attn<<<dim3(16, 44), dim3(256), 0, stream>>>(qkvb, hsc, attnb, xb, wqkvT, pml);
  k_fin<<<dim3(512), dim3(256), 0, stream>>>(attnb, xb, wqkvT, pml, wout, woutT);
  k_gemm<<<dim3(32, 8), dim3(256), 0, stream>>>(attnb, woutT, nullptr, out, kM, kC, kC, kC);
}

// Round 23
// 128.653 us; speedup vs baseline: 1.0013x; 1.0013x over previous
//
#include <hip/hip_runtime.h>
#include <hip/hip_bf16.h>
#include <cstdint>
#include <cstddef>

// ---------------------------------------------------------------------------
// YiJingAttention: x[B,T,C] -> qkv -> causal attn (+rank-1 trigram bias) -> out
// B=2 T=2048 C=1024 H=8 hd=128. All internal matmuls in bf16 MFMA, f32 accum.
// FINAL configuration = measured best, reproduced 5x (128.7-129.2 us):
//   k_prep (cast+transpose fused) -> k_gemm 128^2 (GEMM1) -> k_attn
//   (split-kv flash, nc<=3 LPT schedule, 4 waves x 32 q-rows) -> k_fin
//   (combine+transpose fused) -> k_gemm (GEMM2, f32 out).
// Probed-and-rejected (all measured): 256^2 GEMM tiles (r12/13/15), XCD
// block swizzle (r16), 3-block attn occupancy (r8 spill / r11 null), finer
// nc<=4 splits (r18), 8-wave x 16-row attn (r20). 32x32 MFMA shape rejected
// by analysis: GEMM is barrier/staging-bound, not MFMA-issue-bound.
// ---------------------------------------------------------------------------

namespace {
constexpr int kB = 2, kT = 2048, kC = 1024, kHD = 128;
constexpr int kM = kB * kT;   // 4096 rows
constexpr int kN3 = 3 * kC;   // 3072
constexpr float kScale = 0.08838834764831845f;   // 1/sqrt(128)
constexpr float kInvS3 = 0.57735026918962576f;   // 1/sqrt(3)
constexpr float kL2E  = 1.4426950408889634f;     // log2(e)
}

typedef __bf16 bf16x8 __attribute__((ext_vector_type(8)));
typedef float f32x4 __attribute__((ext_vector_type(4)));
typedef unsigned short u16x8 __attribute__((ext_vector_type(8)));
typedef unsigned short u16x4 __attribute__((ext_vector_type(4)));
typedef unsigned int u32x4 __attribute__((ext_vector_type(4)));

__device__ __forceinline__ unsigned short f2b(float f) {
  return __builtin_bit_cast(unsigned short, (__bf16)f);
}
__device__ __forceinline__ float b2f(unsigned short u) {
  return (float)__builtin_bit_cast(__bf16, u);
}
// async global->LDS, 16B per lane. lds must be wave-uniform base (HW adds lane*16).
__device__ __forceinline__ void gll16(const void* g, void* lds) {
  __builtin_amdgcn_global_load_lds(
      (const __attribute__((address_space(1))) unsigned int*)g,
      (__attribute__((address_space(3))) unsigned int*)lds, 16, 0, 0);
}
__device__ __forceinline__ bf16x8 ldsv(const unsigned short* p) {
  return __builtin_bit_cast(bf16x8, *(const u16x8*)p);
}
// hardware transpose read (m156/m162): 16-lane group collectively reads its
// 4x16 bf16 row-major subtile; lane receives column (lane&15) as 4 bf16.
__device__ __forceinline__ uint2 tr16(const unsigned short* p) {
  uint2 r;
  unsigned off = (unsigned)(uintptr_t)(const __attribute__((address_space(3))) unsigned short*)p;
  asm volatile("ds_read_b64_tr_b16 %0, %1" : "=v"(r) : "v"(off));
  return r;
}

// ---------------- transpose+cast device body (in[R][Cin]f32 -> out[Cin][R]) --
__device__ __forceinline__ void tc_body(const float* __restrict__ in,
                                        unsigned short* __restrict__ out,
                                        int R, int Cin, int bx, int by, int t) {
  __shared__ float tile[64][65];
  const int r0 = by * 64, c0 = bx * 64;
  const int tr = t >> 4, tc4 = (t & 15) * 4;
#pragma unroll
  for (int rr = 0; rr < 4; ++rr) {
    int r = tr + rr * 16;
    float4 v = *(const float4*)&in[(size_t)(r0 + r) * Cin + c0 + tc4];
    tile[r][tc4 + 0] = v.x; tile[r][tc4 + 1] = v.y;
    tile[r][tc4 + 2] = v.z; tile[r][tc4 + 3] = v.w;
  }
  __syncthreads();
#pragma unroll
  for (int rr = 0; rr < 4; ++rr) {
    int c = tr + rr * 16;
    u16x4 o = { f2b(tile[tc4 + 0][c]), f2b(tile[tc4 + 1][c]),
                f2b(tile[tc4 + 2][c]), f2b(tile[tc4 + 3][c]) };
    *(u16x4*)&out[(size_t)(c0 + c) * R + r0 + tc4] = o;
  }
}

// ------ k_prep: blocks [0,4096) cast x->bf16; [4096,4864) transpose wqkv ----
__global__ void k_prep(const float* __restrict__ x, unsigned short* __restrict__ xb,
                       const float* __restrict__ wqkv, unsigned short* __restrict__ wqkvT) {
  const int bid = (int)blockIdx.x;
  const int t = threadIdx.x;
  if (bid < 4096) {
    int i = bid * 256 + t;                      // n4 = 4096*256 exactly
    float4 v = ((const float4*)x)[i];
    u16x4 o = { f2b(v.x), f2b(v.y), f2b(v.z), f2b(v.w) };
    ((u16x4*)xb)[i] = o;
  } else {
    int r = bid - 4096;                         // 768 blocks: 48 x 16
    tc_body(wqkv, wqkvT, kC, kN3, r % 48, r / 48, t);
  }
}

// ----------------- 128x128 bf16 MFMA GEMM, Bt is [N][K] --------------------
// Natural (bx,by) mapping, NO block swizzle (XCD remap measured -1.7us, r16).
__global__ __launch_bounds__(256, 2) void k_gemm(
    const unsigned short* __restrict__ A,
    const unsigned short* __restrict__ Bt,
    unsigned short* __restrict__ Cb,
    float* __restrict__ Cf,
    int M, int N, int K, int ldc) {
  __shared__ unsigned short sA[2][4096];
  __shared__ unsigned short sB[2][4096];
  const int t = threadIdx.x;
  const int lane = t & 63, wave = t >> 6;
  const int g = lane >> 4, c16 = lane & 15;
  const int wr = wave >> 1, wc = wave & 1;
  const int brow = blockIdx.x * 128, bcol = blockIdx.y * 128;
  const int NT = K >> 5;

  f32x4 acc[4][4];
#pragma unroll
  for (int m = 0; m < 4; ++m)
#pragma unroll
    for (int n = 0; n < 4; ++n) acc[m][n] = 0.f;

  auto stage = [&](int buf, int kt) {
    const int k0 = kt * 32;
#pragma unroll
    for (int is = 0; is < 2; ++is) {
      int row = is * 64 + (t >> 2);
      int gs = (t & 3) ^ (row & 3);
      gll16(&A[(size_t)(brow + row) * K + k0 + gs * 8], &sA[buf][is * 2048 + wave * 512]);
      gll16(&Bt[(size_t)(bcol + row) * K + k0 + gs * 8], &sB[buf][is * 2048 + wave * 512]);
    }
  };

  stage(0, 0);
  __syncthreads();
  for (int kt = 0; kt < NT; ++kt) {
    if (kt + 1 < NT) stage((kt + 1) & 1, kt + 1);
    const int buf = kt & 1;
    bf16x8 av[4], bv[4];
#pragma unroll
    for (int m = 0; m < 4; ++m) {
      int row = wr * 64 + m * 16 + c16;
      av[m] = ldsv(&sA[buf][row * 32 + (g ^ (row & 3)) * 8]);
    }
#pragma unroll
    for (int n = 0; n < 4; ++n) {
      int row = wc * 64 + n * 16 + c16;
      bv[n] = ldsv(&sB[buf][row * 32 + (g ^ (row & 3)) * 8]);
    }
    __builtin_amdgcn_s_setprio(1);
#pragma unroll
    for (int m = 0; m < 4; ++m)
#pragma unroll
      for (int n = 0; n < 4; ++n)
        acc[m][n] = __builtin_amdgcn_mfma_f32_16x16x32_bf16(av[m], bv[n], acc[m][n], 0, 0, 0);
    __builtin_amdgcn_s_setprio(0);
    __syncthreads();
  }

  const int orow = brow + wr * 64, ocol = bcol + wc * 64;
  if (Cb != nullptr) {
#pragma unroll
    for (int m = 0; m < 4; ++m)
#pragma unroll
      for (int n = 0; n < 4; ++n)
#pragma unroll
        for (int jj = 0; jj < 4; ++jj)
          Cb[(size_t)(orow + m * 16 + g * 4 + jj) * ldc + ocol + n * 16 + c16] =
              f2b(acc[m][n][jj]);
  } else {
#pragma unroll
    for (int m = 0; m < 4; ++m)
#pragma unroll
      for (int n = 0; n < 4; ++n)
#pragma unroll
        for (int jj = 0; jj < 4; ++jj)
          Cf[(size_t)(orow + m * 16 + g * 4 + jj) * ldc + ocol + n * 16 + c16] =
              acc[m][n][jj];
  }
}

// ---------------- flash attention (split-kv, 128-row q-tiles) --------------
// 256 threads = 4 waves x 32 q-rows. Single-buffered sK, dbuf subtiled sV +
// tr16 HW-transpose reads, LPT split schedule (44 items, nc<=3, sizes 2..11
// size-descending), defer-max (T13), in-register P s-frag->A-frag
// redistribution. Blocks write UNNORMALIZED partial O (bf16) + per-row
// (m,l); k_fin merges <=3 chunks.
__constant__ unsigned char kItem[44] = {
  60, 61,                       // 11 tiles
  62, 56, 57, 58, 52,           // 10
  53, 54, 48, 49,               // 9
  50, 44, 45, 46, 40,           // 8
  41, 42, 36, 37,               // 7
  38, 32, 33, 34, 28,           // 6
  29, 30, 24, 25,               // 5
  26, 20, 21, 22, 16,           // 4
  17, 18, 12, 13, 8, 9,         // 3
  14, 4, 5, 0 };                // 2

__global__ __launch_bounds__(256, 2) void k_attn(
    const unsigned short* __restrict__ qkv,
    const float* __restrict__ head_scales,
    unsigned short* __restrict__ pO0,    // chunk0 partial, final layout [4096][1024]
    unsigned short* __restrict__ pO1,    // chunk1 partial
    unsigned short* __restrict__ pO2,    // chunk2 partial
    float2* __restrict__ pml) {          // [3][16][16][128] (m,l)
  __shared__ unsigned short sK[8192];     // 64 rows x 128 k, XOR-swizzled (single)
  __shared__ unsigned short sV[2][8192];  // [dn 8][kv4 16][4][16] subtiled (dbuf)
  __shared__ float sKp[2][64];

  const int t = threadIdx.x;
  const int lane = t & 63, wave = t >> 6;
  const int g = lane >> 4, c16 = lane & 15;
  const int bh = blockIdx.x;                  // same-bh blocks share an XCD L2
  const int it = kItem[blockIdx.y];
  const int qt = it >> 2, c = it & 3;
  const int n = 2 * qt + 2;
  const int nc = (qt == 0) ? 1 : (qt <= 2) ? 2 : 3;
  const int cbase = n / nc, crem = n % nc;
  const int t0 = c * cbase + (c < crem ? c : crem);
  const int t1 = t0 + cbase + (c < crem ? 1 : 0);

  const int b = bh >> 3, h = bh & 7;
  const float hs = head_scales[h];
  const float sx = (h & 4) ? 1.f : -1.f;
  const float sy = (h & 2) ? 1.f : -1.f;
  const float sz = (h & 1) ? 1.f : -1.f;

  const int q0w = qt * 128 + wave * 32;       // this wave's 32 q-rows
  const size_t rowbase = (size_t)b * kT;

  // Q fragments (B-operand) + per-row bias projection, both 16-row halves
  bf16x8 aq[2][4];
  float qp[2];
#pragma unroll
  for (int m = 0; m < 2; ++m) {
    const unsigned short* qrow = &qkv[(rowbase + q0w + m * 16 + c16) * kN3 + h * kHD];
#pragma unroll
    for (int ks = 0; ks < 4; ++ks) aq[m][ks] = ldsv(qrow + ks * 32 + g * 8);
    qp[m] = hs * kInvS3 * (sx * b2f(qrow[0]) + sy * b2f(qrow[1]) + sz * b2f(qrow[2]));
  }

  float mrow[2] = { -__builtin_inff(), -__builtin_inff() };
  float lrow[2] = { 0.f, 0.f };
  f32x4 oacc[2][8];
#pragma unroll
  for (int m = 0; m < 2; ++m)
#pragma unroll
    for (int dn = 0; dn < 8; ++dn) oacc[m][dn] = 0.f;

  uint2 kpr;       // kp prefetch (wave 0)

  auto stageK = [&](int jt) {
    const int j0 = jt * 64;
#pragma unroll
    for (int is = 0; is < 4; ++is) {
      int row = is * 16 + (t >> 4);
      int gp = t & 15;
      int gs = (gp & 8) | ((gp ^ (row & 7)) & 7);
      gll16(&qkv[(rowbase + j0 + row) * kN3 + kC + h * kHD + gs * 8],
            &sK[is * 2048 + wave * 512]);
    }
  };
  auto stageV = [&](int jt, int buf) {
    const int j0 = jt * 64;
    const int vrow = ((lane >> 3) << 2) + ((lane >> 1) & 3);
    const int vcol = (lane & 1) * 8;
#pragma unroll
    for (int d = 0; d < 2; ++d) {
      const int dn = wave * 2 + d;
#pragma unroll
      for (int hf2 = 0; hf2 < 2; ++hf2) {
        gll16(&qkv[(rowbase + j0 + hf2 * 32 + vrow) * kN3 + 2 * kC + h * kHD
                   + dn * 16 + vcol],
              &sV[buf][dn * 1024 + hf2 * 512]);
      }
    }
  };
  auto loadKp = [&](int jt) {
    if (wave == 0)
      kpr = *(const uint2*)&qkv[(rowbase + jt * 64 + lane) * kN3 + kC + h * kHD];
  };
  auto writeKp = [&](int buf) {
    if (wave == 0) {
      float e0 = b2f((unsigned short)(kpr.x & 0xffffu));
      float e1 = b2f((unsigned short)(kpr.x >> 16));
      float e2 = b2f((unsigned short)(kpr.y & 0xffffu));
      sKp[buf][lane] = kInvS3 * (sx * e0 + sy * e1 + sz * e2);
    }
  };

  // prologue: first tile of this chunk
  stageK(t0); stageV(t0, 0); loadKp(t0);
  writeKp(0);
  __syncthreads();

  for (int jt = t0; jt < t1; ++jt) {
    const int vbuf = (jt - t0) & 1;
    const bool more = (jt + 1 < t1);
    const int j0 = jt * 64;

    // ---- S^T = K Q^T for both 16-row halves (reads sK, single buffer) ----
    f32x4 s[2][4];
#pragma unroll
    for (int m = 0; m < 2; ++m)
#pragma unroll
      for (int nn = 0; nn < 4; ++nn) s[m][nn] = 0.f;
#pragma unroll
    for (int ks = 0; ks < 4; ++ks) {
      bf16x8 kb[4];
#pragma unroll
      for (int nn = 0; nn < 4; ++nn) {
        int gp = ks * 4 + g;
        int gp2 = (gp & 8) | ((gp ^ (c16 & 7)) & 7);
        kb[nn] = ldsv(&sK[(nn * 16 + c16) * 128 + gp2 * 8]);
      }
      __builtin_amdgcn_s_setprio(1);
#pragma unroll
      for (int m = 0; m < 2; ++m)
#pragma unroll
        for (int nn = 0; nn < 4; ++nn)
          s[m][nn] = __builtin_amdgcn_mfma_f32_16x16x32_bf16(kb[nn], aq[m][ks], s[m][nn], 0, 0, 0);
      __builtin_amdgcn_s_setprio(0);
    }

    __syncthreads();   // B1: all waves done reading sK; safe to restage
    if (more) { stageK(jt + 1); stageV(jt + 1, vbuf ^ 1); loadKp(jt + 1); }

    // ---- bias + causal mask + in-lane online softmax, per half ----
    float kpv[4][4];
#pragma unroll
    for (int nn = 0; nn < 4; ++nn)
#pragma unroll
      for (int jj = 0; jj < 4; ++jj) kpv[nn][jj] = sKp[vbuf][nn * 16 + g * 4 + jj];

    const bool edge = (jt >= 2 * qt);         // two diagonal tiles mask
    unsigned int paf[2][2][4];                // [m][ks2][w] A-frag words
#pragma unroll
    for (int m = 0; m < 2; ++m) {
      const int qg = q0w + m * 16 + c16;
      float vmax = -__builtin_inff();
#pragma unroll
      for (int nn = 0; nn < 4; ++nn)
#pragma unroll
        for (int jj = 0; jj < 4; ++jj) {
          float xv = s[m][nn][jj] * kScale + qp[m] * kpv[nn][jj];
          if (edge) {
            int kvg = j0 + nn * 16 + g * 4 + jj;
            xv = (kvg <= qg) ? xv : -__builtin_inff();
          }
          s[m][nn][jj] = xv;
          vmax = fmaxf(vmax, xv);
        }
      vmax = fmaxf(vmax, __shfl_xor(vmax, 16, 64));
      vmax = fmaxf(vmax, __shfl_xor(vmax, 32, 64));

      // defer-max (T13): rescale only when max grows by more than 8
      if (__any(vmax > mrow[m] + 8.f)) {
        float mnew = fmaxf(mrow[m], vmax);
        float mc0 = fmaxf(mnew, -1e30f);
        float alpha = exp2f((mrow[m] - mc0) * kL2E);   // 0 if mrow=-inf
        mrow[m] = mnew;
        lrow[m] *= alpha;
        float ao[4];
#pragma unroll
        for (int jj = 0; jj < 4; ++jj)
          ao[jj] = __shfl(alpha, (lane & 48) | (g * 4 + jj), 64);
#pragma unroll
        for (int dn = 0; dn < 8; ++dn)
#pragma unroll
          for (int jj = 0; jj < 4; ++jj) oacc[m][dn][jj] *= ao[jj];
      }

      // P = exp(s - m) (bounded by e^8 under defer), packed bf16 pairs
      unsigned int pk[4][2];
      {
        const float mc = fmaxf(mrow[m], -1e30f);
        float ls = 0.f;
#pragma unroll
        for (int nn = 0; nn < 4; ++nn) {
          float p0 = exp2f((s[m][nn][0] - mc) * kL2E);
          float p1 = exp2f((s[m][nn][1] - mc) * kL2E);
          float p2 = exp2f((s[m][nn][2] - mc) * kL2E);
          float p3 = exp2f((s[m][nn][3] - mc) * kL2E);
          ls += (p0 + p1) + (p2 + p3);
          pk[nn][0] = (unsigned)f2b(p0) | ((unsigned)f2b(p1) << 16);
          pk[nn][1] = (unsigned)f2b(p2) | ((unsigned)f2b(p3) << 16);
        }
        lrow[m] += ls;
      }
      // redistribute s-frag -> A-frag in register (verified round 7)
#pragma unroll
      for (int ks2 = 0; ks2 < 2; ++ks2)
#pragma unroll
        for (int w = 0; w < 4; ++w) {
          int src = c16 + (((lane >> 4) & 1) * 2 + (w >> 1)) * 16;
          int va  = __shfl((int)pk[2 * ks2][w & 1], src, 64);
          int vb_ = __shfl((int)pk[2 * ks2 + 1][w & 1], src, 64);
          paf[m][ks2][w] = (unsigned)((lane & 32) ? vb_ : va);
        }
    }

    // ---- O += P V (tr16 B-fragments; V-frag read once, both halves) ----
#pragma unroll
    for (int ks2 = 0; ks2 < 2; ++ks2) {
      bf16x8 pa0 = __builtin_bit_cast(bf16x8,
          (u32x4){paf[0][ks2][0], paf[0][ks2][1], paf[0][ks2][2], paf[0][ks2][3]});
      bf16x8 pa1 = __builtin_bit_cast(bf16x8,
          (u32x4){paf[1][ks2][0], paf[1][ks2][1], paf[1][ks2][2], paf[1][ks2][3]});
      uint2 trv[8][2];
#pragma unroll
      for (int dn = 0; dn < 8; ++dn)
#pragma unroll
        for (int hf = 0; hf < 2; ++hf)
          trv[dn][hf] = tr16(&sV[vbuf][dn * 1024 + (ks2 * 8 + 2 * g + hf) * 64 + c16 * 4]);
      asm volatile("s_waitcnt lgkmcnt(0)" ::: "memory");
      __builtin_amdgcn_sched_barrier(0);
      __builtin_amdgcn_s_setprio(1);
#pragma unroll
      for (int dn = 0; dn < 8; ++dn) {
        bf16x8 vb = __builtin_bit_cast(bf16x8,
            (u32x4){trv[dn][0].x, trv[dn][0].y, trv[dn][1].x, trv[dn][1].y});
        oacc[0][dn] = __builtin_amdgcn_mfma_f32_16x16x32_bf16(pa0, vb, oacc[0][dn], 0, 0, 0);
        oacc[1][dn] = __builtin_amdgcn_mfma_f32_16x16x32_bf16(pa1, vb, oacc[1][dn], 0, 0, 0);
      }
      __builtin_amdgcn_s_setprio(0);
    }

    if (more) {
      writeKp(vbuf ^ 1);
      __syncthreads();   // B2: drains staged sK/sV vmem; next tile ready
    }
  }

  // ---- write partials: (m,l) per row + unnormalized O (bf16) ----
  unsigned short* pout = (c == 0) ? pO0 : (c == 1) ? pO1 : pO2;
#pragma unroll
  for (int m = 0; m < 2; ++m) {
    float lt = lrow[m];
    lt += __shfl_xor(lt, 16, 64);
    lt += __shfl_xor(lt, 32, 64);
    if (g == 0) {
      int rowi = wave * 32 + m * 16 + c16;
      pml[c * 32768 + (bh * 16 + qt) * 128 + rowi] = make_float2(mrow[m], lt);
    }
#pragma unroll
    for (int dn = 0; dn < 8; ++dn)
#pragma unroll
      for (int jj = 0; jj < 4; ++jj) {
        int r = q0w + m * 16 + g * 4 + jj;
        pout[(rowbase + r) * kC + h * kHD + dn * 16 + c16] = f2b(oacc[m][dn][jj]);
      }
  }
}

// ---- k_fin: blocks [0,256) combine partials; [256,512) transpose wout -----
__global__ void k_fin(unsigned short* __restrict__ p0,
                      const unsigned short* __restrict__ p1,
                      const unsigned short* __restrict__ p2,
                      const float2* __restrict__ pml,
                      const float* __restrict__ wout,
                      unsigned short* __restrict__ woutT) {
  const int bid = (int)blockIdx.x;
  const int t = threadIdx.x;
  if (bid >= 256) {
    int r = bid - 256;                          // 256 blocks: 16 x 16
    tc_body(wout, woutT, kC, kC, r & 15, r >> 4, t);
    return;
  }
  const int bh = bid & 15, qt = bid >> 4;
  const int row = t >> 1, half = t & 1;          // 128 rows x 2 half-rows(64)
  const int b = bh >> 3, h = bh & 7;
  const size_t base = ((size_t)b * kT + qt * 128 + row) * kC + h * kHD + half * 64;
  const int nc = (qt == 0) ? 1 : (qt <= 2) ? 2 : 3;
  const int mli = (bh * 16 + qt) * 128 + row;
  float2 ml0 = pml[mli];
  float2 ml1 = make_float2(-1e30f, 0.f), ml2 = make_float2(-1e30f, 0.f);
  float mm = ml0.x;
  if (nc > 1) { ml1 = pml[32768 + mli]; mm = fmaxf(mm, ml1.x); }
  if (nc > 2) { ml2 = pml[65536 + mli]; mm = fmaxf(mm, ml2.x); }
  const float w0 = exp2f((ml0.x - mm) * kL2E);
  const float w1 = (nc > 1) ? exp2f((ml1.x - mm) * kL2E) : 0.f;
  const float w2 = (nc > 2) ? exp2f((ml2.x - mm) * kL2E) : 0.f;
  const float inv = 1.0f / (w0 * ml0.y + w1 * ml1.y + w2 * ml2.y);
#pragma unroll
  for (int i = 0; i < 8; ++i) {
    u16x8 o0 = *(const u16x8*)&p0[base + i * 8];
    u16x8 r;
    if (nc == 1) {
#pragma unroll
      for (int j = 0; j < 8; ++j) r[j] = f2b(b2f(o0[j]) * inv);
    } else if (nc == 2) {
      u16x8 o1 = *(const u16x8*)&p1[base + i * 8];
#pragma unroll
      for (int j = 0; j < 8; ++j)
        r[j] = f2b((w0 * b2f(o0[j]) + w1 * b2f(o1[j])) * inv);
    } else {
      u16x8 o1 = *(const u16x8*)&p1[base + i * 8];
      u16x8 o2 = *(const u16x8*)&p2[base + i * 8];
#pragma unroll
      for (int j = 0; j < 8; ++j)
        r[j] = f2b((w0 * b2f(o0[j]) + w1 * b2f(o1[j]) + w2 * b2f(o2[j])) * inv);
    }
    *(u16x8*)&p0[base + i * 8] = r;
  }
}

// ---------------------------------------------------------------------------
extern "C" void kernel_launch(void* const* d_in, const int* in_sizes, int n_in,
                              void* d_out, int out_size, void* d_ws, size_t ws_size,
                              hipStream_t stream) {
  const float* x    = (const float*)d_in[0];
  const float* wqkv = (const float*)d_in[1];
  const float* wout = (const float*)d_in[2];
  const float* hsc  = (const float*)d_in[3];
  char* ws = (char*)d_ws;
  // workspace (48MB exactly):
  //   [0,8M)     xb (GEMM1 A)         -> attn partial1
  //   [8M,16M)   wqkvT (6.3M of 8M)   -> attn partial2
  //   [16M,40M)  qkvb (24M)           -> woutT (first 2M, after attn)
  //   [40M,48M)  attnb: partial0 -> final attn out (in place)
  // (m,l) table lives in d_out (16.8M f32) -- GEMM2 fully overwrites it after.
  unsigned short* xb    = (unsigned short*)(ws);
  unsigned short* wqkvT = (unsigned short*)(ws + 8388608);
  unsigned short* qkvb  = (unsigned short*)(ws + 16777216);
  unsigned short* attnb = (unsigned short*)(ws + 41943040);
  unsigned short* woutT = (unsigned short*)(ws + 16777216);   // reuses qkvb
  float2* pml = (float2*)d_out;
  float* out = (float*)d_out;

  k_prep<<<dim3(4864), dim3(256), 0, stream>>>(x, xb, wqkv, wqkvT);
  k_gemm<<<dim3(32, 24), dim3(256), 0, stream>>>(xb, wqkvT, qkvb, nullptr, kM, kN3, kC, kN3);
  k_attn<<<dim3(16, 44), dim3(256), 0, stream>>>(qkvb, hsc, attnb, xb, wqkvT, pml);
  k_fin<<<dim3(512), dim3(256), 0, stream>>>(attnb, xb, wqkvT, pml, wout, woutT);
  k_gemm<<<dim3(32, 8), dim3(256), 0, stream>>>(attnb, woutT, nullptr, out, kM, kC, kC, kC);
}